// Round 11
// baseline (146.635 us; speedup 1.0000x reference)
//
#include <hip/hip_runtime.h>
#include <hip/hip_bf16.h>

// HeadLayer: B=8, S=2048, E=1024, H=64.
// Inputs (fp32): x[B,S,E], Wq[E,H], Wk[E,H], Wv[E,H]. Output (fp32): [B,S,H].
// ws (bf16): qb[B,S,H] (pre-scaled 1/32), kb[B,S,H], vtb[B,H,S],
//            Wts[16][192][64] (pre-tiled, XOR-swizzled B tiles).

#define BATCH 8
#define SEQ   2048
#define EMB   1024
#define HD    64
#define ROWS  (BATCH*SEQ)      // 16384
#define NTOT  192
#define BK    64
#define NKT   (EMB / BK)       // 16

typedef __attribute__((ext_vector_type(8))) short short8;   // 8 bf16 (4 VGPR)
typedef __attribute__((ext_vector_type(4))) float floatx4;  // MFMA C/D frag

static __device__ __forceinline__ short f2bf(float f) {
  union { __hip_bfloat16 h; short s; } u;
  u.h = __float2bfloat16(f);
  return u.s;
}

static __device__ __forceinline__ short8 pack8(float4 u, float4 v) {
  short8 r;
  r[0] = f2bf(u.x); r[1] = f2bf(u.y); r[2] = f2bf(u.z); r[3] = f2bf(u.w);
  r[4] = f2bf(v.x); r[5] = f2bf(v.y); r[6] = f2bf(v.z); r[7] = f2bf(v.w);
  return r;
}

// async global->LDS, 16 B per lane; LDS dest = wave-uniform base + lane*16
static __device__ __forceinline__ void gload_lds16(const void* g, void* l) {
  __builtin_amdgcn_global_load_lds(
      (const __attribute__((address_space(1))) unsigned int*)g,
      (__attribute__((address_space(3))) unsigned int*)l, 16, 0, 0);
}

// ---------------- W pre-pass: tiled + swizzled B (unchanged R10) ------------
__global__ __launch_bounds__(256) void wt_kernel(
    const float* __restrict__ Wq, const float* __restrict__ Wk,
    const float* __restrict__ Wv, short* __restrict__ Wts) {
  const int id = blockIdx.x * 256 + threadIdx.x;   // 0..24575
  const int kt = id / 1536;
  const int rem = id - kt * 1536;
  const int np = rem >> 3;
  const int s = rem & 7;
  const float* __restrict__ W = (np < 64) ? Wq : ((np < 128) ? Wk : Wv);
  const int n = np & 63;
  const int k0 = kt * BK + (s ^ (np & 7)) * 8;
  short8 o;
#pragma unroll
  for (int u = 0; u < 8; ++u) o[u] = f2bf(W[(size_t)(k0 + u) * HD + n]);
  *(short8*)(Wts + (size_t)id * 8) = o;
}

// ---------------- MFMA QKV projection (unchanged R10) -----------------------
__global__ __launch_bounds__(256, 2) void proj_kernel(
    const float* __restrict__ x, const short* __restrict__ Wts,
    short* __restrict__ qb, short* __restrict__ kb_, short* __restrict__ vtb) {
  __shared__ __align__(16) float As[32 * 64];    // 8 KB
  __shared__ __align__(16) short Bs[192 * 64];   // 24 KB

  const int t = threadIdx.x, lane = t & 63, w = t >> 6;
  const int lo = lane & 15, quad = lane >> 4;
  const int e = lo & 7;
  const int m0 = blockIdx.x * 32;

  const int cc0 = w * 2, cc1 = cc0 + 1;
  const int ar0 = cc0 * 4 + (lane >> 4);
  const int ar1 = cc1 * 4 + (lane >> 4);
  const int aj = lane & 15;
  const float* agp0 = x + (size_t)(m0 + ar0) * EMB + ((aj ^ (ar0 & 7)) * 4);
  const float* agp1 = x + (size_t)(m0 + ar1) * EMB + ((aj ^ (ar1 & 7)) * 4);
  float* alp0 = As + cc0 * 256;
  float* alp1 = As + cc1 * 256;

  const short* bgp = Wts + (size_t)(w * 6) * 512 + lane * 8;
  short* blp = Bs + (w * 6) * 512;

  floatx4 acc[2][3];
#pragma unroll
  for (int mf = 0; mf < 2; ++mf)
#pragma unroll
    for (int j = 0; j < 3; ++j) acc[mf][j] = (floatx4){0.f, 0.f, 0.f, 0.f};

  for (int kt = 0; kt < NKT; ++kt) {
    __syncthreads();
    gload_lds16(agp0 + kt * BK, alp0);
    gload_lds16(agp1 + kt * BK, alp1);
    const short* bg = bgp + (size_t)kt * 12288;
#pragma unroll
    for (int i = 0; i < 6; ++i)
      gload_lds16(bg + i * 512, blp + i * 512);
    __syncthreads();

    short8 af[2][2];
#pragma unroll
    for (int mf = 0; mf < 2; ++mf) {
      const float* Ar = As + (mf * 16 + lo) * 64;
#pragma unroll
      for (int ks = 0; ks < 2; ++ks) {
        const float4 f0 = *(const float4*)(Ar + (((8 * ks + 2 * quad) ^ e) << 2));
        const float4 f1 = *(const float4*)(Ar + (((8 * ks + 2 * quad + 1) ^ e) << 2));
        af[mf][ks] = pack8(f0, f1);
      }
    }
    short8 bf[3][2];
#pragma unroll
    for (int j = 0; j < 3; ++j) {
      const short* Br = Bs + ((w * 3 + j) * 16 + lo) * 64;
#pragma unroll
      for (int ks = 0; ks < 2; ++ks)
        bf[j][ks] = *(const short8*)(Br + (((4 * ks + quad) ^ e) << 3));
    }
#pragma unroll
    for (int ks = 0; ks < 2; ++ks)
#pragma unroll
      for (int j = 0; j < 3; ++j) {
        acc[0][j] = __builtin_amdgcn_mfma_f32_16x16x32_bf16(af[0][ks], bf[j][ks], acc[0][j], 0, 0, 0);
        acc[1][j] = __builtin_amdgcn_mfma_f32_16x16x32_bf16(af[1][ks], bf[j][ks], acc[1][j], 0, 0, 0);
      }
  }

  const int bb = m0 >> 11;
  const int sbase = (m0 & (SEQ - 1)) + quad * 4;
#pragma unroll
  for (int mf = 0; mf < 2; ++mf) {
    const int rowb = m0 + mf * 16 + quad * 4;
#pragma unroll
    for (int j = 0; j < 3; ++j) {
      const int nt = w * 3 + j;
      const floatx4 v = acc[mf][j];
      if (nt < 4) {
#pragma unroll
        for (int r = 0; r < 4; ++r)
          qb[(size_t)(rowb + r) * HD + nt * 16 + lo] = f2bf(v[r] * 0.03125f);
      } else if (nt < 8) {
#pragma unroll
        for (int r = 0; r < 4; ++r)
          kb_[(size_t)(rowb + r) * HD + (nt - 4) * 16 + lo] = f2bf(v[r]);
      } else {
        const int col = (nt - 8) * 16 + lo;
        short4 sv = make_short4(f2bf(v[0]), f2bf(v[1]), f2bf(v[2]), f2bf(v[3]));
        *(short4*)(vtb + ((size_t)bb * HD + col) * SEQ + sbase + mf * 16) = sv;
      }
    }
  }
}

// ---------------- MFMA flash attention v2: global_load_lds + 4 blocks/CU ----
// QT=16, 2-wave blocks (wave = key-half), grid (128,8) = 1024 blocks
// (4 blocks/CU). K/V staged via global_load_lds into unpadded 64-short rows
// with XOR chunk swizzle (slot j holds chunk j^(r&7)): frag reads 2-way (free),
// staging 128B-coalesced. m97 2-barrier loop (verified R10 mechanism).
#define QT 16
#define PSTR 40

__global__ __launch_bounds__(128, 4) void attn_kernel(
    const short* __restrict__ qb, const short* __restrict__ kb,
    const short* __restrict__ vtb, float* __restrict__ out) {
  __shared__ __align__(16) short Ks[64 * 64];      // 8 KB  [key][d] swizzled
  __shared__ __align__(16) short Vs[64 * 64];      // 8 KB  [d][key] swizzled
  __shared__ __align__(16) short Ps[2][16 * PSTR]; // 2.5 KB per-wave P
  __shared__ __align__(16) floatx4 Red[5][64];     // 5 KB combine

  const int b = blockIdx.y;
  const int bx = blockIdx.x;
  const int qx = (bx & 1) ? (127 - (bx >> 1)) : (bx >> 1);  // pair light+heavy
  const int q0 = qx * QT;
  const int t = threadIdx.x, lane = t & 63, w = t >> 6;     // w = key-half
  const int lo = lane & 15, quad = lane >> 4, e = lo & 7;

  // Q A-frags (rows q0..q0+15, bf16 pre-scaled 1/32; same for both waves)
  const short* qp = qb + ((size_t)b * SEQ + q0 + lo) * HD + quad * 8;
  const short8 qf0 = *(const short8*)(qp);
  const short8 qf1 = *(const short8*)(qp + 32);

  // staging geometry: lane -> row-in-group sr, swizzled chunk jg
  const int sr = lane >> 3;
  const int jg = (lane & 7) ^ (sr & 7);
  const short* kaddr = kb + (size_t)b * SEQ * HD + sr * HD + jg * 8;
  const short* vaddr = vtb + (size_t)b * HD * SEQ + (size_t)sr * SEQ + jg * 8;

  floatx4 acc[4];
  float lsum[4] = {0.f, 0.f, 0.f, 0.f};
#pragma unroll
  for (int nt = 0; nt < 4; ++nt) acc[nt] = (floatx4){0.f, 0.f, 0.f, 0.f};

  const int niter = q0 / 64 + 1;
  for (int it = 0; it < niter; ++it) {
    const int j0 = it * 64;
    __syncthreads();           // all waves done reading previous tile
    if (w == 0) {              // wave 0 stages K tile (64 keys x 64 dims)
#pragma unroll
      for (int p = 0; p < 8; ++p)
        gload_lds16(kaddr + (size_t)j0 * HD + p * 512, Ks + p * 512);
    } else {                   // wave 1 stages V^T tile (64 dims x 64 keys)
#pragma unroll
      for (int p = 0; p < 8; ++p)
        gload_lds16(vaddr + (size_t)p * 8 * SEQ + j0, Vs + p * 512);
    }
    __syncthreads();           // staging drained + visible

    // K B-frags: wave's keys w*32 + n2*16 + lo; chunks quad / quad+4, XOR e
    short8 kfr[2][2];
#pragma unroll
    for (int n2 = 0; n2 < 2; ++n2) {
      const int r = w * 32 + n2 * 16 + lo;
      kfr[n2][0] = *(const short8*)(Ks + r * 64 + ((quad ^ e) << 3));
      kfr[n2][1] = *(const short8*)(Ks + r * 64 + (((quad + 4) ^ e) << 3));
    }
    // V B-frags: row d = nt*16+lo, chunk w*4+quad, XOR e
    short8 vfr[4];
#pragma unroll
    for (int nt = 0; nt < 4; ++nt) {
      const int d = nt * 16 + lo;
      vfr[nt] = *(const short8*)(Vs + d * 64 + (((w * 4 + quad) ^ e) << 3));
    }

    // S = Q K^T (16 rows x 32 keys, K-dim 64)
    floatx4 s0 = (floatx4){0.f, 0.f, 0.f, 0.f};
    floatx4 s1 = (floatx4){0.f, 0.f, 0.f, 0.f};
    s0 = __builtin_amdgcn_mfma_f32_16x16x32_bf16(qf0, kfr[0][0], s0, 0, 0, 0);
    s0 = __builtin_amdgcn_mfma_f32_16x16x32_bf16(qf1, kfr[0][1], s0, 0, 0, 0);
    s1 = __builtin_amdgcn_mfma_f32_16x16x32_bf16(qf0, kfr[1][0], s1, 0, 0, 0);
    s1 = __builtin_amdgcn_mfma_f32_16x16x32_bf16(qf1, kfr[1][1], s1, 0, 0, 0);

    // p = exp(s), mask only on diagonal tile
    const bool diag = (j0 + 64 > q0);
    short* Pw = Ps[w];
#pragma unroll
    for (int r = 0; r < 4; ++r) {
      float e0 = __expf(s0[r]);
      float e1 = __expf(s1[r]);
      if (diag) {
        const int key0 = j0 + w * 32 + lo;
        const int qrow = q0 + quad * 4 + r;
        e0 = (key0 <= qrow) ? e0 : 0.f;
        e1 = (key0 + 16 <= qrow) ? e1 : 0.f;
      }
      lsum[r] += e0 + e1;
      Pw[(quad * 4 + r) * PSTR + lo] = f2bf(e0);
      Pw[(quad * 4 + r) * PSTR + 16 + lo] = f2bf(e1);
    }
    // P: C-layout -> A-layout via wave-private LDS (K=32 exact)
    const short8 pf = *(const short8*)(&Pw[lo * PSTR + quad * 8]);
#pragma unroll
    for (int nt = 0; nt < 4; ++nt)
      acc[nt] = __builtin_amdgcn_mfma_f32_16x16x32_bf16(pf, vfr[nt], acc[nt], 0, 0, 0);
  }

  // row-sum across the 16-lane key group
#pragma unroll
  for (int d = 1; d < 16; d <<= 1) {
#pragma unroll
    for (int r = 0; r < 4; ++r) lsum[r] += __shfl_xor(lsum[r], d);
  }

  // combine the two key-half partials
  if (w == 1) {
#pragma unroll
    for (int nt = 0; nt < 4; ++nt) Red[nt][lane] = acc[nt];
    Red[4][lane] = (floatx4){lsum[0], lsum[1], lsum[2], lsum[3]};
  }
  __syncthreads();
  if (w == 0) {
    const floatx4 lp = Red[4][lane];
#pragma unroll
    for (int nt = 0; nt < 4; ++nt) {
      const floatx4 o = acc[nt] + Red[nt][lane];
#pragma unroll
      for (int r = 0; r < 4; ++r)
        out[((size_t)b * SEQ + q0 + quad * 4 + r) * HD + nt * 16 + lo] =
            o[r] / (lsum[r] + lp[r]);
    }
  }
}

extern "C" void kernel_launch(void* const* d_in, const int* in_sizes, int n_in,
                              void* d_out, int out_size, void* d_ws, size_t ws_size,
                              hipStream_t stream) {
  const float* x  = (const float*)d_in[0];
  const float* Wq = (const float*)d_in[1];
  const float* Wk = (const float*)d_in[2];
  const float* Wv = (const float*)d_in[3];
  float* out = (float*)d_out;
  short* ws = (short*)d_ws;
  short* qbp = ws;
  short* kbp = ws + (size_t)ROWS * HD;
  short* vtp = ws + (size_t)2 * ROWS * HD;
  short* Wts = ws + (size_t)3 * ROWS * HD;   // 384 KB; total 6.68 MB <= ws_size

  wt_kernel<<<dim3(96), 256, 0, stream>>>(Wq, Wk, Wv, Wts);
  proj_kernel<<<dim3(ROWS / 32), 256, 0, stream>>>(x, Wts, qbp, kbp, vtp);
  attn_kernel<<<dim3(SEQ / QT, BATCH), 128, 0, stream>>>(qbp, kbp, vtp, out);
}